// Round 1
// baseline (244.253 us; speedup 1.0000x reference)
//
#include <hip/hip_runtime.h>
#include <math.h>

// Problem constants (B=8,S=4096,D=1024,E=64,G=4,K=2, temperature=1)
#define TOKENS   32768
#define DDIM     1024
#define TPB      64                   // tokens per block (4 m-tiles per wave)
#define NBLOCKS  (TOKENS / TPB)       // 512 blocks x 128 threads (2 waves = K-halves)

// Output layout (flat float32, tuple concat: idx, scores, probs, importance, load)
#define OFF_SCORES 65536
#define OFF_PROBS  131072
#define OFF_IMP    2228224
#define OFF_LOAD   2228288

typedef __attribute__((ext_vector_type(8))) short  short8;  // 8 bf16 = 4 VGPR (MFMA A/B frag)
typedef __attribute__((ext_vector_type(4))) float  f32x4;   // MFMA C/D frag
typedef __attribute__((ext_vector_type(4))) int    intx4;

// Pre-split W fragments: [ks(32)][nt(5)][lvl(3)][lane(64)] x 16B. 480 KB, L2-resident.
// Rows 0..63 = experts, 64..67 = groups, 68..79 = zero pad.
__device__ __attribute__((aligned(16))) short wfrag[32 * 5 * 3 * 64 * 8];

// bf16 round-to-nearest-even of x, returned as the fp32 bit pattern.
__device__ inline unsigned rne_hi(float x) {
  unsigned u = __float_as_uint(x);
  unsigned r = u + 0x7fffu + ((u >> 16) & 1u);
  return r & 0xffff0000u;
}

// Split x (fp32) into 3 RNE-bf16 terms: x = a1 + a2 + a3 + O(2^-27 |x|).
__device__ inline void split3(const float* xv, short8& f1, short8& f2, short8& f3) {
  int o1[4], o2[4], o3[4];
  #pragma unroll
  for (int p = 0; p < 4; ++p) {
    float x0 = xv[2*p], x1 = xv[2*p+1];
    unsigned h0 = rne_hi(x0), h1 = rne_hi(x1);
    o1[p] = (int)((h0 >> 16) | (h1 & 0xffff0000u));
    float r0 = x0 - __uint_as_float(h0);
    float r1 = x1 - __uint_as_float(h1);
    unsigned g0 = rne_hi(r0), g1 = rne_hi(r1);
    o2[p] = (int)((g0 >> 16) | (g1 & 0xffff0000u));
    float s0 = r0 - __uint_as_float(g0);
    float s1 = r1 - __uint_as_float(g1);
    unsigned w0 = rne_hi(s0), w1 = rne_hi(s1);
    o3[p] = (int)((w0 >> 16) | (w1 & 0xffff0000u));
  }
  intx4 t1 = {o1[0], o1[1], o1[2], o1[3]};
  intx4 t2 = {o2[0], o2[1], o2[2], o2[3]};
  intx4 t3 = {o3[0], o3[1], o3[2], o3[3]};
  f1 = __builtin_bit_cast(short8, t1);
  f2 = __builtin_bit_cast(short8, t2);
  f3 = __builtin_bit_cast(short8, t3);
}

// Build W fragment splits. 160 blocks (nt*32+ks) x 64 threads.
// Block 0 additionally zero-inits the importance/load accumulators in out
// (stream-ordered before router_kernel, so no workspace needed).
__global__ void prep_kernel(const float* __restrict__ Wg, const float* __restrict__ We,
                            float* __restrict__ out) {
  const int nt   = blockIdx.x >> 5;   // 0..4
  const int ks   = blockIdx.x & 31;   // 0..31
  const int lane = threadIdx.x & 63;
  if (blockIdx.x == 0) {
    out[OFF_IMP  + lane] = 0.f;
    out[OFF_LOAD + lane] = 0.f;
  }
  const int row  = nt * 16 + (lane & 15);
  const int k0   = ks * 32 + (lane >> 4) * 8;
  float xv[8];
  #pragma unroll
  for (int j = 0; j < 8; ++j) {
    float v = 0.f;
    if (row < 64)      v = We[(size_t)row * DDIM + k0 + j];
    else if (row < 68) v = Wg[(size_t)(row - 64) * DDIM + k0 + j];
    xv[j] = v;
  }
  short8 f1, f2, f3;
  split3(xv, f1, f2, f3);
  short8* dst = (short8*)wfrag + (((size_t)ks * 5 + nt) * 3) * 64 + lane;
  dst[0]   = f1;
  dst[64]  = f2;
  dst[128] = f3;
}

// v3's exact per-token arithmetic graph; 4 m-tiles per wave. waves_per_eu(1,1)
// gives 1 wave/SIMD with the full unified VGPR/AGPR budget (~512, m08).
// Depth-2 A prefetch (cur/nx1/nx2): with 1 wave/SIMD there is no TLP, so HBM
// latency (~900 cy) must be ILP-hidden; depth-1 put exactly the Little's-law
// minimum (~2.3 KB/SIMD avg) in flight — depth-2 doubles the margin.
__global__ __launch_bounds__(128)
__attribute__((amdgpu_waves_per_eu(1, 1)))
void router_kernel(const float* __restrict__ x,
                   float* __restrict__ out) {
  __shared__ __attribute__((aligned(16))) float el[TPB * 88];  // logits, stride 88
  __shared__ int cnt[64];
  const int tid    = threadIdx.x;
  const int lane   = tid & 63;
  const int khalf  = tid >> 6;     // wave id = K-half (512-wide, sequential 16 k-steps)
  const int quad   = lane >> 4;
  const int m      = lane & 15;
  const int tokblk = blockIdx.x * TPB;

  if (tid < 64) cnt[tid] = 0;

  // MFMA A-operand gather: lane holds A[row=m][k=quad*8+j]; four 16-token m-tiles.
  const float* apb = x + (size_t)(tokblk + m) * DDIM + khalf * 512 + quad * 8;

  // v3-verified numerics: a1b1 chain isolated in ahi; all cross terms in alo.
  f32x4 ahi[4][5], alo[4][5];
  #pragma unroll
  for (int mt = 0; mt < 4; ++mt)
    #pragma unroll
    for (int nt = 0; nt < 5; ++nt) { ahi[mt][nt] = 0.f; alo[mt][nt] = 0.f; }

  // depth-2 A prefetch: cur = ks, nx1 = ks+1, nx2 = ks+2 (issued in-loop)
  float4 cur[8], nx1[8], nx2[8];
  #pragma unroll
  for (int mt = 0; mt < 4; ++mt) {
    const float* p = apb + (size_t)(mt * 16) * DDIM;
    cur[mt * 2]     = *(const float4*)(p);
    cur[mt * 2 + 1] = *(const float4*)(p + 4);
    nx1[mt * 2]     = *(const float4*)(p + 32);
    nx1[mt * 2 + 1] = *(const float4*)(p + 36);
  }

  for (int ks = 0; ks < 16; ++ks) {
    // B fragments for this K-step — issued first; split3 VALU covers their latency
    const short8* bp = (const short8*)wfrag + ((size_t)(khalf * 16 + ks) * 15) * 64 + lane;
    short8 fb[5][3];
    #pragma unroll
    for (int nt = 0; nt < 5; ++nt) {
      fb[nt][0] = bp[nt * 192];
      fb[nt][1] = bp[nt * 192 + 64];
      fb[nt][2] = bp[nt * 192 + 128];
    }
    // prefetch A for ks+2 (clamped on tail iters, dup reads are L1/L2 hits)
    const int kpf = (ks + 2 < 16) ? (ks + 2) : 15;
    #pragma unroll
    for (int mt = 0; mt < 4; ++mt) {
      const float* p = apb + (size_t)(mt * 16) * DDIM + kpf * 32;
      nx2[mt * 2]     = *(const float4*)(p);
      nx2[mt * 2 + 1] = *(const float4*)(p + 4);
    }
    // split current A -> 3 bf16 fragments per m-tile
    short8 fa[4][3];
    #pragma unroll
    for (int mt = 0; mt < 4; ++mt) {
      float av[8] = {cur[mt*2].x, cur[mt*2].y, cur[mt*2].z, cur[mt*2].w,
                     cur[mt*2+1].x, cur[mt*2+1].y, cur[mt*2+1].z, cur[mt*2+1].w};
      split3(av, fa[mt][0], fa[mt][1], fa[mt][2]);
    }
    // 8-pass split MFMA: a1b1 -> hi; all cross terms -> lo (only a3b3 dropped)
    // per-accumulator chain order preserved exactly (bit-exact vs v3/v8/v10)
    #pragma unroll
    for (int nt = 0; nt < 5; ++nt)
      #pragma unroll
      for (int mt = 0; mt < 4; ++mt) {
        ahi[mt][nt] = __builtin_amdgcn_mfma_f32_16x16x32_bf16(fa[mt][0], fb[nt][0], ahi[mt][nt], 0, 0, 0);
        f32x4 c = alo[mt][nt];
        c = __builtin_amdgcn_mfma_f32_16x16x32_bf16(fa[mt][0], fb[nt][1], c, 0, 0, 0);
        c = __builtin_amdgcn_mfma_f32_16x16x32_bf16(fa[mt][1], fb[nt][0], c, 0, 0, 0);
        c = __builtin_amdgcn_mfma_f32_16x16x32_bf16(fa[mt][1], fb[nt][1], c, 0, 0, 0);
        c = __builtin_amdgcn_mfma_f32_16x16x32_bf16(fa[mt][0], fb[nt][2], c, 0, 0, 0);
        c = __builtin_amdgcn_mfma_f32_16x16x32_bf16(fa[mt][2], fb[nt][0], c, 0, 0, 0);
        c = __builtin_amdgcn_mfma_f32_16x16x32_bf16(fa[mt][1], fb[nt][2], c, 0, 0, 0);
        c = __builtin_amdgcn_mfma_f32_16x16x32_bf16(fa[mt][2], fb[nt][1], c, 0, 0, 0);
        alo[mt][nt] = c;
      }
    #pragma unroll
    for (int i = 0; i < 8; ++i) { cur[i] = nx1[i]; nx1[i] = nx2[i]; }
  }

  // ---- K-half combine, v3's exact order: el = S1; el += S0 ----
  // C/D layout: col(n)=lane&15, row(m)=quad*4+reg
  if (khalf == 1) {
    #pragma unroll
    for (int mt = 0; mt < 4; ++mt)
      #pragma unroll
      for (int nt = 0; nt < 5; ++nt)
        #pragma unroll
        for (int r = 0; r < 4; ++r)
          el[(mt * 16 + quad * 4 + r) * 88 + nt * 16 + m] = ahi[mt][nt][r] + alo[mt][nt][r];
  }
  __syncthreads();
  if (khalf == 0) {
    #pragma unroll
    for (int mt = 0; mt < 4; ++mt)
      #pragma unroll
      for (int nt = 0; nt < 5; ++nt)
        #pragma unroll
        for (int r = 0; r < 4; ++r) {
          const int idx = (mt * 16 + quad * 4 + r) * 88 + nt * 16 + m;
          el[idx] += ahi[mt][nt][r] + alo[mt][nt][r];
        }
  }
  __syncthreads();

  // ---- epilogue: one token per thread (tid<64) ----
  if (tid < TPB) {
    const int t = tid;
    float* row = el + t * 88;
    const float g0 = row[64], g1 = row[65], g2 = row[66], g3 = row[67];
    int g = 0; float gb = g0;
    if (g1 > gb) { g = 1; gb = g1; }
    if (g2 > gb) { g = 2; gb = g2; }
    if (g3 > gb) { g = 3; gb = g3; }
    const int base = g << 4;
    float l[16];
    #pragma unroll
    for (int e = 0; e < 16; ++e) l[e] = row[base + e];
    int i1 = 0; float v1 = l[0];
    #pragma unroll
    for (int e = 1; e < 16; ++e) if (l[e] > v1) { i1 = e; v1 = l[e]; }
    int i2 = -1; float v2 = 0.f;
    #pragma unroll
    for (int e = 0; e < 16; ++e) {
      if (e == i1) continue;
      if (i2 < 0 || l[e] > v2) { i2 = e; v2 = l[e]; }
    }
    float pr[16]; float s = 0.f;
    #pragma unroll
    for (int e = 0; e < 16; ++e) { pr[e] = expf(l[e] - v1); s += pr[e]; }
    const float inv = 1.f / s;
    #pragma unroll
    for (int c = 0; c < 64; ++c) row[c] = 0.f;
    #pragma unroll
    for (int e = 0; e < 16; ++e) row[base + e] = pr[e] * inv;
    const size_t T = (size_t)tokblk + t;
    out[2*T]     = (float)(base + i1);
    out[2*T + 1] = (float)(base + i2);
    const float e2 = expf(v2 - v1);
    const float si = 1.f / (1.f + e2);
    out[OFF_SCORES + 2*T]     = si;
    out[OFF_SCORES + 2*T + 1] = e2 * si;
    atomicAdd(&cnt[base + i1], 1);
    atomicAdd(&cnt[base + i2], 1);
  }
  __syncthreads();

  // coalesced probs_full write
  for (int i = tid; i < TPB * 64; i += 128) {
    const int t = i >> 6, c = i & 63;
    out[OFF_PROBS + (((size_t)(tokblk + t)) << 6) + c] = el[t * 88 + c];
  }
  // block-partial importance & counts -> pre-scaled global atomics directly
  // into out (power-of-two scaling is exact, so rounding is bit-identical to
  // the old sum-then-scale finalize pass)
  if (tid < 64) {
    const int e = tid;
    float s = 0.f;
    #pragma unroll 4
    for (int t = 0; t < TPB; ++t) s += el[t * 88 + e];
    atomicAdd(&out[OFF_IMP  + e], s * (1.0f / 32768.0f));
    atomicAdd(&out[OFF_LOAD + e], (float)cnt[e] * (1.0f / 65536.0f));
  }
}

extern "C" void kernel_launch(void* const* d_in, const int* in_sizes, int n_in,
                              void* d_out, int out_size, void* d_ws, size_t ws_size,
                              hipStream_t stream) {
  (void)in_sizes; (void)n_in; (void)out_size; (void)d_ws; (void)ws_size;
  const float* x  = (const float*)d_in[0];   // [8,4096,1024]
  const float* Wg = (const float*)d_in[1];   // [4,1024]
  const float* We = (const float*)d_in[2];   // [64,1024]
  float* out = (float*)d_out;
  hipLaunchKernelGGL(prep_kernel, dim3(160), dim3(64), 0, stream, Wg, We, out);
  hipLaunchKernelGGL(router_kernel, dim3(NBLOCKS), dim3(128), 0, stream, x, out);
}

// Round 2
// 220.587 us; speedup vs baseline: 1.1073x; 1.1073x over previous
//
#include <hip/hip_runtime.h>
#include <math.h>

// Problem constants (B=8,S=4096,D=1024,E=64,G=4,K=2, temperature=1)
#define TOKENS   32768
#define DDIM     1024
#define TPB      32                   // tokens per block (2 m-tiles per wave)
#define NBLOCKS  (TOKENS / TPB)       // 1024 blocks x 128 threads (2 waves = K-halves)

// Output layout (flat float32, tuple concat: idx, scores, probs, importance, load)
#define OFF_SCORES 65536
#define OFF_PROBS  131072
#define OFF_IMP    2228224
#define OFF_LOAD   2228288

#define NSLOT 32              // atomic spreading for importance/load partials

typedef __attribute__((ext_vector_type(8))) short  short8;  // 8 bf16 = 4 VGPR (MFMA A/B frag)
typedef __attribute__((ext_vector_type(4))) float  f32x4;   // MFMA C/D frag
typedef __attribute__((ext_vector_type(4))) int    intx4;

// Pre-split W fragments: [ks(32)][nt(5)][lvl(3)][lane(64)] x 16B. 480 KB, L2-resident.
// Rows 0..63 = experts, 64..67 = groups, 68..79 = zero pad.
__device__ __attribute__((aligned(16))) short wfrag[32 * 5 * 3 * 64 * 8];

// bf16 round-to-nearest-even of x, returned as the fp32 bit pattern.
__device__ inline unsigned rne_hi(float x) {
  unsigned u = __float_as_uint(x);
  unsigned r = u + 0x7fffu + ((u >> 16) & 1u);
  return r & 0xffff0000u;
}

// Split x (fp32) into 3 RNE-bf16 terms: x = a1 + a2 + a3 + O(2^-27 |x|).
__device__ inline void split3(const float* xv, short8& f1, short8& f2, short8& f3) {
  int o1[4], o2[4], o3[4];
  #pragma unroll
  for (int p = 0; p < 4; ++p) {
    float x0 = xv[2*p], x1 = xv[2*p+1];
    unsigned h0 = rne_hi(x0), h1 = rne_hi(x1);
    o1[p] = (int)((h0 >> 16) | (h1 & 0xffff0000u));
    float r0 = x0 - __uint_as_float(h0);
    float r1 = x1 - __uint_as_float(h1);
    unsigned g0 = rne_hi(r0), g1 = rne_hi(r1);
    o2[p] = (int)((g0 >> 16) | (g1 & 0xffff0000u));
    float s0 = r0 - __uint_as_float(g0);
    float s1 = r1 - __uint_as_float(g1);
    unsigned w0 = rne_hi(s0), w1 = rne_hi(s1);
    o3[p] = (int)((w0 >> 16) | (w1 & 0xffff0000u));
  }
  intx4 t1 = {o1[0], o1[1], o1[2], o1[3]};
  intx4 t2 = {o2[0], o2[1], o2[2], o2[3]};
  intx4 t3 = {o3[0], o3[1], o3[2], o3[3]};
  f1 = __builtin_bit_cast(short8, t1);
  f2 = __builtin_bit_cast(short8, t2);
  f3 = __builtin_bit_cast(short8, t3);
}

// Build W fragment splits. 160 blocks (nt*32+ks) x 64 threads.
__global__ void prep_kernel(const float* __restrict__ Wg, const float* __restrict__ We) {
  const int nt   = blockIdx.x >> 5;   // 0..4
  const int ks   = blockIdx.x & 31;   // 0..31
  const int lane = threadIdx.x & 63;
  const int row  = nt * 16 + (lane & 15);
  const int k0   = ks * 32 + (lane >> 4) * 8;
  float xv[8];
  #pragma unroll
  for (int j = 0; j < 8; ++j) {
    float v = 0.f;
    if (row < 64)      v = We[(size_t)row * DDIM + k0 + j];
    else if (row < 68) v = Wg[(size_t)(row - 64) * DDIM + k0 + j];
    xv[j] = v;
  }
  short8 f1, f2, f3;
  split3(xv, f1, f2, f3);
  short8* dst = (short8*)wfrag + (((size_t)ks * 5 + nt) * 3) * 64 + lane;
  dst[0]   = f1;
  dst[64]  = f2;
  dst[128] = f3;
}

// Same per-token arithmetic graph as the verified 210 µs kernel (bit-exact:
// identical MFMA chain order, split terms, and K-half combine order). Only
// the grid mapping changed: 2 m-tiles/wave (TPB=32) x 1024 blocks instead of
// 4 m-tiles x 512. Rationale (round-1 counters): Occupancy 9.5% / VALUBusy
// 22% / MfmaUtil 15% -> the 1-wave/SIMD pin left ~65% of cycles as unhidden
// L2/L3 latency. Halving per-wave registers (acc 160->80 VGPR) lets 2 waves
// co-reside per SIMD, hiding stalls with TLP instead of ILP.
__global__ __launch_bounds__(128)
__attribute__((amdgpu_waves_per_eu(2)))
void router_kernel(const float* __restrict__ x,
                   float* __restrict__ out,
                   float* __restrict__ ws) {
  __shared__ __attribute__((aligned(16))) float el[TPB * 88];  // logits, stride 88
  __shared__ int cnt[64];
  const int tid    = threadIdx.x;
  const int lane   = tid & 63;
  const int khalf  = tid >> 6;     // wave id = K-half (512-wide, sequential 16 k-steps)
  const int quad   = lane >> 4;
  const int m      = lane & 15;
  const int tokblk = blockIdx.x * TPB;

  if (tid < 64) cnt[tid] = 0;

  // MFMA A-operand gather: lane holds A[row=m][k=quad*8+j]; two 16-token m-tiles.
  const float* apb = x + (size_t)(tokblk + m) * DDIM + khalf * 512 + quad * 8;

  // a1b1 chain isolated in ahi; all cross terms in alo (verified numerics).
  f32x4 ahi[2][5], alo[2][5];
  #pragma unroll
  for (int mt = 0; mt < 2; ++mt)
    #pragma unroll
    for (int nt = 0; nt < 5; ++nt) { ahi[mt][nt] = 0.f; alo[mt][nt] = 0.f; }

  // depth-1 A prefetch: cur = ks, loaded into nxt during previous step
  float4 cur[4], nxt[4];
  #pragma unroll
  for (int mt = 0; mt < 2; ++mt) {
    const float* p = apb + (size_t)(mt * 16) * DDIM;
    cur[mt * 2]     = *(const float4*)(p);
    cur[mt * 2 + 1] = *(const float4*)(p + 4);
  }

  for (int ks = 0; ks < 16; ++ks) {
    // B fragments for this K-step — issued first; split3 VALU covers their latency
    const short8* bp = (const short8*)wfrag + ((size_t)(khalf * 16 + ks) * 15) * 64 + lane;
    short8 fb[5][3];
    #pragma unroll
    for (int nt = 0; nt < 5; ++nt) {
      fb[nt][0] = bp[nt * 192];
      fb[nt][1] = bp[nt * 192 + 64];
      fb[nt][2] = bp[nt * 192 + 128];
    }
    // prefetch A for ks+1 (clamped on last iter, discarded)
    const int kpf = (ks + 1 < 16) ? (ks + 1) : 15;
    #pragma unroll
    for (int mt = 0; mt < 2; ++mt) {
      const float* p = apb + (size_t)(mt * 16) * DDIM + kpf * 32;
      nxt[mt * 2]     = *(const float4*)(p);
      nxt[mt * 2 + 1] = *(const float4*)(p + 4);
    }
    // split current A -> 3 bf16 fragments per m-tile
    short8 fa[2][3];
    #pragma unroll
    for (int mt = 0; mt < 2; ++mt) {
      float av[8] = {cur[mt*2].x, cur[mt*2].y, cur[mt*2].z, cur[mt*2].w,
                     cur[mt*2+1].x, cur[mt*2+1].y, cur[mt*2+1].z, cur[mt*2+1].w};
      split3(av, fa[mt][0], fa[mt][1], fa[mt][2]);
    }
    // 8-pass split MFMA: a1b1 -> hi; all cross terms -> lo (only a3b3 dropped)
    // per-accumulator chain order preserved exactly (bit-exact vs verified)
    #pragma unroll
    for (int nt = 0; nt < 5; ++nt)
      #pragma unroll
      for (int mt = 0; mt < 2; ++mt) {
        ahi[mt][nt] = __builtin_amdgcn_mfma_f32_16x16x32_bf16(fa[mt][0], fb[nt][0], ahi[mt][nt], 0, 0, 0);
        f32x4 c = alo[mt][nt];
        c = __builtin_amdgcn_mfma_f32_16x16x32_bf16(fa[mt][0], fb[nt][1], c, 0, 0, 0);
        c = __builtin_amdgcn_mfma_f32_16x16x32_bf16(fa[mt][1], fb[nt][0], c, 0, 0, 0);
        c = __builtin_amdgcn_mfma_f32_16x16x32_bf16(fa[mt][1], fb[nt][1], c, 0, 0, 0);
        c = __builtin_amdgcn_mfma_f32_16x16x32_bf16(fa[mt][0], fb[nt][2], c, 0, 0, 0);
        c = __builtin_amdgcn_mfma_f32_16x16x32_bf16(fa[mt][2], fb[nt][0], c, 0, 0, 0);
        c = __builtin_amdgcn_mfma_f32_16x16x32_bf16(fa[mt][1], fb[nt][2], c, 0, 0, 0);
        c = __builtin_amdgcn_mfma_f32_16x16x32_bf16(fa[mt][2], fb[nt][1], c, 0, 0, 0);
        alo[mt][nt] = c;
      }
    #pragma unroll
    for (int i = 0; i < 4; ++i) cur[i] = nxt[i];
  }

  // ---- K-half combine, verified order: el = S1; el += S0 ----
  // C/D layout: col(n)=lane&15, row(m)=quad*4+reg
  if (khalf == 1) {
    #pragma unroll
    for (int mt = 0; mt < 2; ++mt)
      #pragma unroll
      for (int nt = 0; nt < 5; ++nt)
        #pragma unroll
        for (int r = 0; r < 4; ++r)
          el[(mt * 16 + quad * 4 + r) * 88 + nt * 16 + m] = ahi[mt][nt][r] + alo[mt][nt][r];
  }
  __syncthreads();
  if (khalf == 0) {
    #pragma unroll
    for (int mt = 0; mt < 2; ++mt)
      #pragma unroll
      for (int nt = 0; nt < 5; ++nt)
        #pragma unroll
        for (int r = 0; r < 4; ++r) {
          const int idx = (mt * 16 + quad * 4 + r) * 88 + nt * 16 + m;
          el[idx] += ahi[mt][nt][r] + alo[mt][nt][r];
        }
  }
  __syncthreads();

  // ---- epilogue: one token per thread (tid<32) ----
  if (tid < TPB) {
    const int t = tid;
    float* row = el + t * 88;
    const float g0 = row[64], g1 = row[65], g2 = row[66], g3 = row[67];
    int g = 0; float gb = g0;
    if (g1 > gb) { g = 1; gb = g1; }
    if (g2 > gb) { g = 2; gb = g2; }
    if (g3 > gb) { g = 3; gb = g3; }
    const int base = g << 4;
    float l[16];
    #pragma unroll
    for (int e = 0; e < 16; ++e) l[e] = row[base + e];
    int i1 = 0; float v1 = l[0];
    #pragma unroll
    for (int e = 1; e < 16; ++e) if (l[e] > v1) { i1 = e; v1 = l[e]; }
    int i2 = -1; float v2 = 0.f;
    #pragma unroll
    for (int e = 0; e < 16; ++e) {
      if (e == i1) continue;
      if (i2 < 0 || l[e] > v2) { i2 = e; v2 = l[e]; }
    }
    float pr[16]; float s = 0.f;
    #pragma unroll
    for (int e = 0; e < 16; ++e) { pr[e] = expf(l[e] - v1); s += pr[e]; }
    const float inv = 1.f / s;
    #pragma unroll
    for (int c = 0; c < 64; ++c) row[c] = 0.f;
    #pragma unroll
    for (int e = 0; e < 16; ++e) row[base + e] = pr[e] * inv;
    const size_t T = (size_t)tokblk + t;
    out[2*T]     = (float)(base + i1);
    out[2*T + 1] = (float)(base + i2);
    const float e2 = expf(v2 - v1);
    const float si = 1.f / (1.f + e2);
    out[OFF_SCORES + 2*T]     = si;
    out[OFF_SCORES + 2*T + 1] = e2 * si;
    atomicAdd(&cnt[base + i1], 1);
    atomicAdd(&cnt[base + i2], 1);
  }
  __syncthreads();

  // coalesced probs_full write
  for (int i = tid; i < TPB * 64; i += 128) {
    const int t = i >> 6, c = i & 63;
    out[OFF_PROBS + (((size_t)(tokblk + t)) << 6) + c] = el[t * 88 + c];
  }
  // block-partial importance & counts -> slot-spread global atomics
  // (NSLOT=32 with 1024 blocks keeps per-address contention at 32, matching
  // the verified round-0 scheme; round-1's direct-to-out atomics serialized
  // 512-way on 2 cache lines and cost ~tens of µs)
  if (tid < 64) {
    const int e = tid;
    float s = 0.f;
    #pragma unroll 4
    for (int t = 0; t < TPB; ++t) s += el[t * 88 + e];
    const int slot = (blockIdx.x & (NSLOT - 1)) * 128;
    atomicAdd(&ws[slot + e], s);
    atomicAdd(&ws[slot + 64 + e], (float)cnt[e]);
  }
}

__global__ void finalize_kernel(const float* __restrict__ ws, float* __restrict__ out) {
  const int e = threadIdx.x;
  if (e < 64) {
    float imp = 0.f, cf = 0.f;
    #pragma unroll
    for (int s = 0; s < NSLOT; ++s) {
      imp += ws[s * 128 + e];
      cf  += ws[s * 128 + 64 + e];
    }
    out[OFF_IMP  + e] = imp * (1.0f / 32768.0f);
    out[OFF_LOAD + e] = cf  * (1.0f / 65536.0f);   // counts sum == B*S*K
  }
}

extern "C" void kernel_launch(void* const* d_in, const int* in_sizes, int n_in,
                              void* d_out, int out_size, void* d_ws, size_t ws_size,
                              hipStream_t stream) {
  (void)in_sizes; (void)n_in; (void)out_size; (void)ws_size;
  const float* x  = (const float*)d_in[0];   // [8,4096,1024]
  const float* Wg = (const float*)d_in[1];   // [4,1024]
  const float* We = (const float*)d_in[2];   // [64,1024]
  float* out = (float*)d_out;
  float* ws  = (float*)d_ws;                 // NSLOT x (64 importance + 64 counts)
  hipMemsetAsync(d_ws, 0, NSLOT * 128 * sizeof(float), stream);
  hipLaunchKernelGGL(prep_kernel, dim3(160), dim3(64), 0, stream, Wg, We);
  hipLaunchKernelGGL(router_kernel, dim3(NBLOCKS), dim3(128), 0, stream, x, out, ws);
  hipLaunchKernelGGL(finalize_kernel, dim3(1), dim3(64), 0, stream, ws, out);
}

// Round 3
// 208.445 us; speedup vs baseline: 1.1718x; 1.0582x over previous
//
#include <hip/hip_runtime.h>
#include <math.h>

// Problem constants (B=8,S=4096,D=1024,E=64,G=4,K=2, temperature=1)
#define TOKENS   32768
#define DDIM     1024
#define TPB      64                   // tokens per block
#define NBLOCKS  (TOKENS / TPB)       // 512 blocks x 256 threads (4 waves: khalf x mhalf)

// Output layout (flat float32, tuple concat: idx, scores, probs, importance, load)
#define OFF_SCORES 65536
#define OFF_PROBS  131072
#define OFF_IMP    2228224
#define OFF_LOAD   2228288

#define NSLOT 16              // atomic spreading for importance/load partials

typedef __attribute__((ext_vector_type(8))) short  short8;  // 8 bf16 = 4 VGPR (MFMA A/B frag)
typedef __attribute__((ext_vector_type(4))) float  f32x4;   // MFMA C/D frag
typedef __attribute__((ext_vector_type(4))) int    intx4;

// Pre-split W fragments: [ks(32)][nt(5)][lvl(3)][lane(64)] x 16B. 480 KB, L2-resident.
// Rows 0..63 = experts, 64..67 = groups, 68..79 = zero pad.
__device__ __attribute__((aligned(16))) short wfrag[32 * 5 * 3 * 64 * 8];

// bf16 round-to-nearest-even of x, returned as the fp32 bit pattern.
__device__ inline unsigned rne_hi(float x) {
  unsigned u = __float_as_uint(x);
  unsigned r = u + 0x7fffu + ((u >> 16) & 1u);
  return r & 0xffff0000u;
}

// Split x (fp32) into 3 RNE-bf16 terms: x = a1 + a2 + a3 + O(2^-27 |x|).
__device__ inline void split3(const float* xv, short8& f1, short8& f2, short8& f3) {
  int o1[4], o2[4], o3[4];
  #pragma unroll
  for (int p = 0; p < 4; ++p) {
    float x0 = xv[2*p], x1 = xv[2*p+1];
    unsigned h0 = rne_hi(x0), h1 = rne_hi(x1);
    o1[p] = (int)((h0 >> 16) | (h1 & 0xffff0000u));
    float r0 = x0 - __uint_as_float(h0);
    float r1 = x1 - __uint_as_float(h1);
    unsigned g0 = rne_hi(r0), g1 = rne_hi(r1);
    o2[p] = (int)((g0 >> 16) | (g1 & 0xffff0000u));
    float s0 = r0 - __uint_as_float(g0);
    float s1 = r1 - __uint_as_float(g1);
    unsigned w0 = rne_hi(s0), w1 = rne_hi(s1);
    o3[p] = (int)((w0 >> 16) | (w1 & 0xffff0000u));
  }
  intx4 t1 = {o1[0], o1[1], o1[2], o1[3]};
  intx4 t2 = {o2[0], o2[1], o2[2], o2[3]};
  intx4 t3 = {o3[0], o3[1], o3[2], o3[3]};
  f1 = __builtin_bit_cast(short8, t1);
  f2 = __builtin_bit_cast(short8, t2);
  f3 = __builtin_bit_cast(short8, t3);
}

// Build W fragment splits. 160 blocks (nt*32+ks) x 64 threads.
__global__ void prep_kernel(const float* __restrict__ Wg, const float* __restrict__ We) {
  const int nt   = blockIdx.x >> 5;   // 0..4
  const int ks   = blockIdx.x & 31;   // 0..31
  const int lane = threadIdx.x & 63;
  const int row  = nt * 16 + (lane & 15);
  const int k0   = ks * 32 + (lane >> 4) * 8;
  float xv[8];
  #pragma unroll
  for (int j = 0; j < 8; ++j) {
    float v = 0.f;
    if (row < 64)      v = We[(size_t)row * DDIM + k0 + j];
    else if (row < 68) v = Wg[(size_t)(row - 64) * DDIM + k0 + j];
    xv[j] = v;
  }
  short8 f1, f2, f3;
  split3(xv, f1, f2, f3);
  short8* dst = (short8*)wfrag + (((size_t)ks * 5 + nt) * 3) * 64 + lane;
  dst[0]   = f1;
  dst[64]  = f2;
  dst[128] = f3;
}

// Bit-exact per-token arithmetic vs the verified 210 µs kernel: identical
// 8-pass MFMA chain order per accumulator, identical sequential ks order per
// khalf, identical el=S1; el+=S0 combine, identical epilogue.
// Structural change only: 512 blocks x 256 threads (4 waves = khalf x mhalf,
// 2 m-tiles each) -> 2048 waves = 2/SIMD TLP (round 0 had exactly 1/SIMD and
// ~75% latency stall). The block's 30 KB of B-fragments per k-step is staged
// once into LDS and shared by all 4 waves (round 2 showed per-wave L2 B-reads
// don't amortize at 2 m-tiles/wave: 490 MB L2 traffic). T14 issue-early /
// write-late staging: next-step B -> regs right after this step's fb ds_reads
// (latency hides under split3+MFMA), regs -> LDS after the end-of-step barrier.
__global__ __launch_bounds__(256)
__attribute__((amdgpu_waves_per_eu(2)))
void router_kernel(const float* __restrict__ x,
                   float* __restrict__ out,
                   float* __restrict__ ws) {
  __shared__ __attribute__((aligned(16))) float el[TPB * 88];   // logits, stride 88
  __shared__ __attribute__((aligned(16))) short8 bstage[30 * 64]; // 30 KB: both khalves' 15 frags
  __shared__ int cnt[64];
  const int tid    = threadIdx.x;
  const int lane   = tid & 63;
  const int wv     = tid >> 6;      // 0..3
  const int khalf  = wv >> 1;       // K-half (512-wide, sequential 16 k-steps)
  const int mhalf  = wv & 1;        // which pair of 16-token m-tiles
  const int quad   = lane >> 4;
  const int m      = lane & 15;
  const int tokblk = blockIdx.x * TPB;

  if (tid < 64) cnt[tid] = 0;

  // MFMA A-operand gather: lane holds A[row=m][k=quad*8+j]; two 16-token m-tiles.
  const float* apb = x + (size_t)(tokblk + mhalf * 32 + m) * DDIM + khalf * 512 + quad * 8;
  const short8* wsrc = (const short8*)wfrag;

  // a1b1 chain isolated in ahi; all cross terms in alo (verified numerics).
  f32x4 ahi[2][5], alo[2][5];
  #pragma unroll
  for (int mt = 0; mt < 2; ++mt)
    #pragma unroll
    for (int nt = 0; nt < 5; ++nt) { ahi[mt][nt] = 0.f; alo[mt][nt] = 0.f; }

  // depth-1 A prefetch
  float4 cur[4], nxt[4];
  #pragma unroll
  for (int mt = 0; mt < 2; ++mt) {
    const float* p = apb + (size_t)(mt * 16) * DDIM;
    cur[mt * 2]     = *(const float4*)(p);
    cur[mt * 2 + 1] = *(const float4*)(p + 4);
  }

  // B staging registers: chunk c = wv + 4*j (c<30); c<15 -> khalf0 frag c,
  // c>=15 -> khalf1 frag c-15. Each chunk is one contiguous 1 KB fragment.
  short8 breg[8];
  #pragma unroll
  for (int j = 0; j < 8; ++j) {
    const int c = wv + 4 * j;
    if (c < 30) {
      const int ksg = (c < 15) ? 0 : 16;
      const int fr  = (c < 15) ? c : c - 15;
      breg[j] = wsrc[((size_t)ksg * 15 + fr) * 64 + lane];
    }
  }
  #pragma unroll
  for (int j = 0; j < 8; ++j) {
    const int c = wv + 4 * j;
    if (c < 30) bstage[c * 64 + lane] = breg[j];
  }
  __syncthreads();

  for (int ks = 0; ks < 16; ++ks) {
    // B fragments for this K-step from LDS (staged last step; shared by block)
    short8 fb[5][3];
    #pragma unroll
    for (int nt = 0; nt < 5; ++nt) {
      const short8* bp = &bstage[(khalf * 15 + nt * 3) * 64 + lane];
      fb[nt][0] = bp[0];
      fb[nt][1] = bp[64];
      fb[nt][2] = bp[128];
    }
    // issue next-step B chunk loads early (latency hides under split3+MFMA)
    if (ks < 15) {
      #pragma unroll
      for (int j = 0; j < 8; ++j) {
        const int c = wv + 4 * j;
        if (c < 30) {
          const int ksg = (c < 15) ? (ks + 1) : (16 + ks + 1);
          const int fr  = (c < 15) ? c : c - 15;
          breg[j] = wsrc[((size_t)ksg * 15 + fr) * 64 + lane];
        }
      }
    }
    // A prefetch for ks+1 (clamped on last iter, discarded)
    const int kpf = (ks + 1 < 16) ? (ks + 1) : 15;
    #pragma unroll
    for (int mt = 0; mt < 2; ++mt) {
      const float* p = apb + (size_t)(mt * 16) * DDIM + kpf * 32;
      nxt[mt * 2]     = *(const float4*)(p);
      nxt[mt * 2 + 1] = *(const float4*)(p + 4);
    }
    // per-mt split3 + 8-pass MFMA (one fa-triple live at a time: saves VGPRs;
    // cross-(mt,nt) order irrelevant, per-accumulator chain order preserved)
    #pragma unroll
    for (int mt = 0; mt < 2; ++mt) {
      float av[8] = {cur[mt*2].x, cur[mt*2].y, cur[mt*2].z, cur[mt*2].w,
                     cur[mt*2+1].x, cur[mt*2+1].y, cur[mt*2+1].z, cur[mt*2+1].w};
      short8 fa0, fa1, fa2;
      split3(av, fa0, fa1, fa2);
      #pragma unroll
      for (int nt = 0; nt < 5; ++nt) {
        ahi[mt][nt] = __builtin_amdgcn_mfma_f32_16x16x32_bf16(fa0, fb[nt][0], ahi[mt][nt], 0, 0, 0);
        f32x4 c = alo[mt][nt];
        c = __builtin_amdgcn_mfma_f32_16x16x32_bf16(fa0, fb[nt][1], c, 0, 0, 0);
        c = __builtin_amdgcn_mfma_f32_16x16x32_bf16(fa1, fb[nt][0], c, 0, 0, 0);
        c = __builtin_amdgcn_mfma_f32_16x16x32_bf16(fa1, fb[nt][1], c, 0, 0, 0);
        c = __builtin_amdgcn_mfma_f32_16x16x32_bf16(fa0, fb[nt][2], c, 0, 0, 0);
        c = __builtin_amdgcn_mfma_f32_16x16x32_bf16(fa2, fb[nt][0], c, 0, 0, 0);
        c = __builtin_amdgcn_mfma_f32_16x16x32_bf16(fa1, fb[nt][2], c, 0, 0, 0);
        c = __builtin_amdgcn_mfma_f32_16x16x32_bf16(fa2, fb[nt][1], c, 0, 0, 0);
        alo[mt][nt] = c;
      }
    }
    #pragma unroll
    for (int i = 0; i < 4; ++i) cur[i] = nxt[i];
    // write-late: publish next step's B after all waves consumed this step's
    if (ks < 15) {
      __syncthreads();
      #pragma unroll
      for (int j = 0; j < 8; ++j) {
        const int c = wv + 4 * j;
        if (c < 30) bstage[c * 64 + lane] = breg[j];
      }
      __syncthreads();
    }
  }

  // ---- K-half combine, verified order: el = S1; el += S0 ----
  // C/D layout: col(n)=lane&15, row(m)=quad*4+reg
  if (khalf == 1) {
    #pragma unroll
    for (int mt = 0; mt < 2; ++mt)
      #pragma unroll
      for (int nt = 0; nt < 5; ++nt)
        #pragma unroll
        for (int r = 0; r < 4; ++r)
          el[(mhalf * 32 + mt * 16 + quad * 4 + r) * 88 + nt * 16 + m] = ahi[mt][nt][r] + alo[mt][nt][r];
  }
  __syncthreads();
  if (khalf == 0) {
    #pragma unroll
    for (int mt = 0; mt < 2; ++mt)
      #pragma unroll
      for (int nt = 0; nt < 5; ++nt)
        #pragma unroll
        for (int r = 0; r < 4; ++r) {
          const int idx = (mhalf * 32 + mt * 16 + quad * 4 + r) * 88 + nt * 16 + m;
          el[idx] += ahi[mt][nt][r] + alo[mt][nt][r];
        }
  }
  __syncthreads();

  // ---- epilogue: one token per thread (tid<64) ----
  if (tid < TPB) {
    const int t = tid;
    float* row = el + t * 88;
    const float g0 = row[64], g1 = row[65], g2 = row[66], g3 = row[67];
    int g = 0; float gb = g0;
    if (g1 > gb) { g = 1; gb = g1; }
    if (g2 > gb) { g = 2; gb = g2; }
    if (g3 > gb) { g = 3; gb = g3; }
    const int base = g << 4;
    float l[16];
    #pragma unroll
    for (int e = 0; e < 16; ++e) l[e] = row[base + e];
    int i1 = 0; float v1 = l[0];
    #pragma unroll
    for (int e = 1; e < 16; ++e) if (l[e] > v1) { i1 = e; v1 = l[e]; }
    int i2 = -1; float v2 = 0.f;
    #pragma unroll
    for (int e = 0; e < 16; ++e) {
      if (e == i1) continue;
      if (i2 < 0 || l[e] > v2) { i2 = e; v2 = l[e]; }
    }
    float pr[16]; float s = 0.f;
    #pragma unroll
    for (int e = 0; e < 16; ++e) { pr[e] = expf(l[e] - v1); s += pr[e]; }
    const float inv = 1.f / s;
    #pragma unroll
    for (int c = 0; c < 64; ++c) row[c] = 0.f;
    #pragma unroll
    for (int e = 0; e < 16; ++e) row[base + e] = pr[e] * inv;
    const size_t T = (size_t)tokblk + t;
    out[2*T]     = (float)(base + i1);
    out[2*T + 1] = (float)(base + i2);
    const float e2 = expf(v2 - v1);
    const float si = 1.f / (1.f + e2);
    out[OFF_SCORES + 2*T]     = si;
    out[OFF_SCORES + 2*T + 1] = e2 * si;
    atomicAdd(&cnt[base + i1], 1);
    atomicAdd(&cnt[base + i2], 1);
  }
  __syncthreads();

  // coalesced probs_full write (256 threads, 16 iters)
  for (int i = tid; i < TPB * 64; i += 256) {
    const int t = i >> 6, c = i & 63;
    out[OFF_PROBS + (((size_t)(tokblk + t)) << 6) + c] = el[t * 88 + c];
  }
  // block-partial importance & counts -> slot-spread global atomics
  // (512 blocks / 16 slots = 32-way contention, the verified round-0 scheme)
  if (tid < 64) {
    const int e = tid;
    float s = 0.f;
    #pragma unroll 4
    for (int t = 0; t < TPB; ++t) s += el[t * 88 + e];
    const int slot = (blockIdx.x & (NSLOT - 1)) * 128;
    atomicAdd(&ws[slot + e], s);
    atomicAdd(&ws[slot + 64 + e], (float)cnt[e]);
  }
}

__global__ void finalize_kernel(const float* __restrict__ ws, float* __restrict__ out) {
  const int e = threadIdx.x;
  if (e < 64) {
    float imp = 0.f, cf = 0.f;
    #pragma unroll
    for (int s = 0; s < NSLOT; ++s) {
      imp += ws[s * 128 + e];
      cf  += ws[s * 128 + 64 + e];
    }
    out[OFF_IMP  + e] = imp * (1.0f / 32768.0f);
    out[OFF_LOAD + e] = cf  * (1.0f / 65536.0f);   // counts sum == B*S*K
  }
}

extern "C" void kernel_launch(void* const* d_in, const int* in_sizes, int n_in,
                              void* d_out, int out_size, void* d_ws, size_t ws_size,
                              hipStream_t stream) {
  (void)in_sizes; (void)n_in; (void)out_size; (void)ws_size;
  const float* x  = (const float*)d_in[0];   // [8,4096,1024]
  const float* Wg = (const float*)d_in[1];   // [4,1024]
  const float* We = (const float*)d_in[2];   // [64,1024]
  float* out = (float*)d_out;
  float* ws  = (float*)d_ws;                 // NSLOT x (64 importance + 64 counts)
  hipMemsetAsync(d_ws, 0, NSLOT * 128 * sizeof(float), stream);
  hipLaunchKernelGGL(prep_kernel, dim3(160), dim3(64), 0, stream, Wg, We);
  hipLaunchKernelGGL(router_kernel, dim3(NBLOCKS), dim3(256), 0, stream, x, out, ws);
  hipLaunchKernelGGL(finalize_kernel, dim3(1), dim3(64), 0, stream, ws, out);
}

// Round 4
// 205.813 us; speedup vs baseline: 1.1868x; 1.0128x over previous
//
#include <hip/hip_runtime.h>
#include <math.h>

// Problem constants (B=8,S=4096,D=1024,E=64,G=4,K=2, temperature=1)
#define TOKENS   32768
#define DDIM     1024
#define TPB      64                   // tokens per block
#define NBLOCKS  (TOKENS / TPB)       // 512 blocks x 256 threads (4 waves: khalf x mhalf)

// Output layout (flat float32, tuple concat: idx, scores, probs, importance, load)
#define OFF_SCORES 65536
#define OFF_PROBS  131072
#define OFF_IMP    2228224
#define OFF_LOAD   2228288

#define NSLOT 16              // atomic spreading for importance/load partials

typedef __attribute__((ext_vector_type(8))) short  short8;  // 8 bf16 = 4 VGPR (MFMA A/B frag)
typedef __attribute__((ext_vector_type(4))) float  f32x4;   // MFMA C/D frag
typedef __attribute__((ext_vector_type(4))) int    intx4;

// Pre-split W fragments: [ks(32)][nt(5)][lvl(3)][lane(64)] x 16B. 480 KB, L2-resident.
// Rows 0..63 = experts, 64..67 = groups, 68..79 = zero pad.
__device__ __attribute__((aligned(16))) short wfrag[32 * 5 * 3 * 64 * 8];

// bf16 round-to-nearest-even of x, returned as the fp32 bit pattern.
__device__ inline unsigned rne_hi(float x) {
  unsigned u = __float_as_uint(x);
  unsigned r = u + 0x7fffu + ((u >> 16) & 1u);
  return r & 0xffff0000u;
}

// Split x (fp32) into 3 RNE-bf16 terms: x = a1 + a2 + a3 + O(2^-27 |x|).
__device__ inline void split3(const float* xv, short8& f1, short8& f2, short8& f3) {
  int o1[4], o2[4], o3[4];
  #pragma unroll
  for (int p = 0; p < 4; ++p) {
    float x0 = xv[2*p], x1 = xv[2*p+1];
    unsigned h0 = rne_hi(x0), h1 = rne_hi(x1);
    o1[p] = (int)((h0 >> 16) | (h1 & 0xffff0000u));
    float r0 = x0 - __uint_as_float(h0);
    float r1 = x1 - __uint_as_float(h1);
    unsigned g0 = rne_hi(r0), g1 = rne_hi(r1);
    o2[p] = (int)((g0 >> 16) | (g1 & 0xffff0000u));
    float s0 = r0 - __uint_as_float(g0);
    float s1 = r1 - __uint_as_float(g1);
    unsigned w0 = rne_hi(s0), w1 = rne_hi(s1);
    o3[p] = (int)((w0 >> 16) | (w1 & 0xffff0000u));
  }
  intx4 t1 = {o1[0], o1[1], o1[2], o1[3]};
  intx4 t2 = {o2[0], o2[1], o2[2], o2[3]};
  intx4 t3 = {o3[0], o3[1], o3[2], o3[3]};
  f1 = __builtin_bit_cast(short8, t1);
  f2 = __builtin_bit_cast(short8, t2);
  f3 = __builtin_bit_cast(short8, t3);
}

// Build W fragment splits. 160 blocks (nt*32+ks) x 64 threads.
// Blocks 0..31 also zero the ws accumulators (replaces the hipMemsetAsync).
__global__ void prep_kernel(const float* __restrict__ Wg, const float* __restrict__ We,
                            float* __restrict__ ws) {
  const int nt   = blockIdx.x >> 5;   // 0..4
  const int ks   = blockIdx.x & 31;   // 0..31
  const int lane = threadIdx.x & 63;
  if (blockIdx.x < 32) ws[blockIdx.x * 64 + lane] = 0.f;   // NSLOT*128 = 2048 floats
  const int row  = nt * 16 + (lane & 15);
  const int k0   = ks * 32 + (lane >> 4) * 8;
  float xv[8];
  #pragma unroll
  for (int j = 0; j < 8; ++j) {
    float v = 0.f;
    if (row < 64)      v = We[(size_t)row * DDIM + k0 + j];
    else if (row < 68) v = Wg[(size_t)(row - 64) * DDIM + k0 + j];
    xv[j] = v;
  }
  short8 f1, f2, f3;
  split3(xv, f1, f2, f3);
  short8* dst = (short8*)wfrag + (((size_t)ks * 5 + nt) * 3) * 64 + lane;
  dst[0]   = f1;
  dst[64]  = f2;
  dst[128] = f3;
}

// Bit-exact per-token arithmetic vs the verified kernel (identical per-
// accumulator MFMA chain order, sequential ks per khalf, el=S1; el+=S0
// combine, identical epilogue). Round-4 structural changes, driven by the
// "vmcnt(0) drain at every __syncthreads" model:
//  - double-buffered bstage -> ONE barrier per k-step (was 2); el unioned
//    over buf0 (last step ks=15 reads only buf1, so no aliasing race).
//  - ALL VMEM issued at the TOP of the step (breg first, A second): at the
//    end-of-step drain every outstanding load is ~700-900cy old (covered by
//    split3+MFMA), so the drain is ~free and the ds_write's breg wait is a
//    counted vmcnt(8) that leaves the A-loads in flight.
//  - per-nt fb streaming (24 live regs vs 60) with nt-outer/mt-inner order
//    (independent accumulators; per-chain order preserved -> bit-exact),
//    keeping peak VGPR ~240 so 2 waves/EU fits spill-free.
__global__ __launch_bounds__(256)
__attribute__((amdgpu_waves_per_eu(2)))
void router_kernel(const float* __restrict__ x,
                   float* __restrict__ out,
                   float* __restrict__ ws) {
  // union: [0,61440) = bstage dbuf (2 x 30 chunks x 64 lanes x 16B);
  //        el (64*88*4 = 22528 B) overlays buf0, used only after the loop.
  __shared__ __attribute__((aligned(16))) char smem[61440 + 256];
  float*  el     = (float*)smem;
  short8* bstage = (short8*)smem;
  int*    cnt    = (int*)(smem + 61440);
  const int tid    = threadIdx.x;
  const int lane   = tid & 63;
  const int wv     = tid >> 6;      // 0..3
  const int khalf  = wv >> 1;       // K-half (512-wide, sequential 16 k-steps)
  const int mhalf  = wv & 1;        // which pair of 16-token m-tiles
  const int quad   = lane >> 4;
  const int m      = lane & 15;
  const int tokblk = blockIdx.x * TPB;

  if (tid < 64) cnt[tid] = 0;

  // MFMA A-operand gather: lane holds A[row=m][k=quad*8+j]; two 16-token m-tiles.
  const float* apb = x + (size_t)(tokblk + mhalf * 32 + m) * DDIM + khalf * 512 + quad * 8;
  const short8* wsrc = (const short8*)wfrag;

  // a1b1 chain isolated in ahi; all cross terms in alo (verified numerics).
  f32x4 ahi[2][5], alo[2][5];
  #pragma unroll
  for (int mt = 0; mt < 2; ++mt)
    #pragma unroll
    for (int nt = 0; nt < 5; ++nt) { ahi[mt][nt] = 0.f; alo[mt][nt] = 0.f; }

  // A for ks=0
  float4 cur[4], nxt[4];
  #pragma unroll
  for (int mt = 0; mt < 2; ++mt) {
    const float* p = apb + (size_t)(mt * 16) * DDIM;
    cur[mt * 2]     = *(const float4*)(p);
    cur[mt * 2 + 1] = *(const float4*)(p + 4);
  }

  // Prologue: stage ks=0 B into buf0. chunk c = wv + 4*j; c<15 -> khalf0
  // frag c, c>=15 -> khalf1 frag c-15. Each chunk = one contiguous 1 KB frag.
  {
    short8 breg[8];
    #pragma unroll
    for (int j = 0; j < 8; ++j) {
      const int c = wv + 4 * j;
      if (c < 30) {
        const int ksg = (c < 15) ? 0 : 16;
        const int fr  = (c < 15) ? c : c - 15;
        breg[j] = wsrc[((size_t)ksg * 15 + fr) * 64 + lane];
      }
    }
    #pragma unroll
    for (int j = 0; j < 8; ++j) {
      const int c = wv + 4 * j;
      if (c < 30) bstage[c * 64 + lane] = breg[j];
    }
  }
  __syncthreads();

  for (int ks = 0; ks < 16; ++ks) {
    const int pb = ks & 1;
    // ---- VMEM issue, top of step: breg (ks+1) first, then A (ks+1) ----
    short8 breg[8];
    if (ks < 15) {
      #pragma unroll
      for (int j = 0; j < 8; ++j) {
        const int c = wv + 4 * j;
        if (c < 30) {
          const int ksg = (c < 15) ? (ks + 1) : (16 + ks + 1);
          const int fr  = (c < 15) ? c : c - 15;
          breg[j] = wsrc[((size_t)ksg * 15 + fr) * 64 + lane];
        }
      }
    }
    const int kpf = (ks + 1 < 16) ? (ks + 1) : 15;
    #pragma unroll
    for (int mt = 0; mt < 2; ++mt) {
      const float* p = apb + (size_t)(mt * 16) * DDIM + kpf * 32;
      nxt[mt * 2]     = *(const float4*)(p);
      nxt[mt * 2 + 1] = *(const float4*)(p + 4);
    }
    // ---- split3 for both m-tiles ----
    short8 fa[2][3];
    #pragma unroll
    for (int mt = 0; mt < 2; ++mt) {
      float av[8] = {cur[mt*2].x, cur[mt*2].y, cur[mt*2].z, cur[mt*2].w,
                     cur[mt*2+1].x, cur[mt*2+1].y, cur[mt*2+1].z, cur[mt*2+1].w};
      split3(av, fa[mt][0], fa[mt][1], fa[mt][2]);
    }
    // ---- nt loop, per-nt fb streaming from buf[pb] ----
    const short8* bbase = &bstage[(size_t)pb * 1920 + (size_t)khalf * 15 * 64 + lane];
    short8 fb0 = bbase[0], fb1 = bbase[64], fb2 = bbase[128];
    #pragma unroll
    for (int nt = 0; nt < 5; ++nt) {
      short8 n0, n1, n2;
      if (nt < 4) {
        n0 = bbase[(nt + 1) * 192];
        n1 = bbase[(nt + 1) * 192 + 64];
        n2 = bbase[(nt + 1) * 192 + 128];
      }
      // 8-pass split MFMA: a1b1 -> hi; cross terms -> lo (a3b3 dropped).
      // Per-accumulator chain order preserved exactly (bit-exact).
      #pragma unroll
      for (int mt = 0; mt < 2; ++mt) {
        ahi[mt][nt] = __builtin_amdgcn_mfma_f32_16x16x32_bf16(fa[mt][0], fb0, ahi[mt][nt], 0, 0, 0);
        f32x4 c = alo[mt][nt];
        c = __builtin_amdgcn_mfma_f32_16x16x32_bf16(fa[mt][0], fb1, c, 0, 0, 0);
        c = __builtin_amdgcn_mfma_f32_16x16x32_bf16(fa[mt][1], fb0, c, 0, 0, 0);
        c = __builtin_amdgcn_mfma_f32_16x16x32_bf16(fa[mt][1], fb1, c, 0, 0, 0);
        c = __builtin_amdgcn_mfma_f32_16x16x32_bf16(fa[mt][0], fb2, c, 0, 0, 0);
        c = __builtin_amdgcn_mfma_f32_16x16x32_bf16(fa[mt][2], fb0, c, 0, 0, 0);
        c = __builtin_amdgcn_mfma_f32_16x16x32_bf16(fa[mt][1], fb2, c, 0, 0, 0);
        c = __builtin_amdgcn_mfma_f32_16x16x32_bf16(fa[mt][2], fb1, c, 0, 0, 0);
        alo[mt][nt] = c;
      }
      if (nt < 4) { fb0 = n0; fb1 = n1; fb2 = n2; }
    }
    // ---- publish next B to buf[pb^1]; single barrier per step ----
    if (ks < 15) {
      #pragma unroll
      for (int j = 0; j < 8; ++j) {
        const int c = wv + 4 * j;
        if (c < 30) bstage[(size_t)(pb ^ 1) * 1920 + c * 64 + lane] = breg[j];
      }
      __syncthreads();
    }
    #pragma unroll
    for (int i = 0; i < 4; ++i) cur[i] = nxt[i];
  }

  // ---- K-half combine, verified order: el = S1; el += S0 ----
  // Safe vs the union: step 15 read only buf1 (bytes 30720+); el is 22528 B
  // inside buf0, whose last readers retired at the end-of-ks=14 barrier.
  // C/D layout: col(n)=lane&15, row(m)=quad*4+reg
  if (khalf == 1) {
    #pragma unroll
    for (int mt = 0; mt < 2; ++mt)
      #pragma unroll
      for (int nt = 0; nt < 5; ++nt)
        #pragma unroll
        for (int r = 0; r < 4; ++r)
          el[(mhalf * 32 + mt * 16 + quad * 4 + r) * 88 + nt * 16 + m] = ahi[mt][nt][r] + alo[mt][nt][r];
  }
  __syncthreads();
  if (khalf == 0) {
    #pragma unroll
    for (int mt = 0; mt < 2; ++mt)
      #pragma unroll
      for (int nt = 0; nt < 5; ++nt)
        #pragma unroll
        for (int r = 0; r < 4; ++r) {
          const int idx = (mhalf * 32 + mt * 16 + quad * 4 + r) * 88 + nt * 16 + m;
          el[idx] += ahi[mt][nt][r] + alo[mt][nt][r];
        }
  }
  __syncthreads();

  // ---- epilogue: one token per thread (tid<64) ----
  if (tid < TPB) {
    const int t = tid;
    float* row = el + t * 88;
    const float g0 = row[64], g1 = row[65], g2 = row[66], g3 = row[67];
    int g = 0; float gb = g0;
    if (g1 > gb) { g = 1; gb = g1; }
    if (g2 > gb) { g = 2; gb = g2; }
    if (g3 > gb) { g = 3; gb = g3; }
    const int base = g << 4;
    float l[16];
    #pragma unroll
    for (int e = 0; e < 16; ++e) l[e] = row[base + e];
    int i1 = 0; float v1 = l[0];
    #pragma unroll
    for (int e = 1; e < 16; ++e) if (l[e] > v1) { i1 = e; v1 = l[e]; }
    int i2 = -1; float v2 = 0.f;
    #pragma unroll
    for (int e = 0; e < 16; ++e) {
      if (e == i1) continue;
      if (i2 < 0 || l[e] > v2) { i2 = e; v2 = l[e]; }
    }
    float pr[16]; float s = 0.f;
    #pragma unroll
    for (int e = 0; e < 16; ++e) { pr[e] = expf(l[e] - v1); s += pr[e]; }
    const float inv = 1.f / s;
    #pragma unroll
    for (int c = 0; c < 64; ++c) row[c] = 0.f;
    #pragma unroll
    for (int e = 0; e < 16; ++e) row[base + e] = pr[e] * inv;
    const size_t T = (size_t)tokblk + t;
    out[2*T]     = (float)(base + i1);
    out[2*T + 1] = (float)(base + i2);
    const float e2 = expf(v2 - v1);
    const float si = 1.f / (1.f + e2);
    out[OFF_SCORES + 2*T]     = si;
    out[OFF_SCORES + 2*T + 1] = e2 * si;
    atomicAdd(&cnt[base + i1], 1);
    atomicAdd(&cnt[base + i2], 1);
  }
  __syncthreads();

  // coalesced probs_full write (256 threads, 16 iters)
  for (int i = tid; i < TPB * 64; i += 256) {
    const int t = i >> 6, c = i & 63;
    out[OFF_PROBS + (((size_t)(tokblk + t)) << 6) + c] = el[t * 88 + c];
  }
  // block-partial importance & counts -> slot-spread global atomics
  // (512 blocks / 16 slots = 32-way contention, verified scheme)
  if (tid < 64) {
    const int e = tid;
    float s = 0.f;
    #pragma unroll 4
    for (int t = 0; t < TPB; ++t) s += el[t * 88 + e];
    const int slot = (blockIdx.x & (NSLOT - 1)) * 128;
    atomicAdd(&ws[slot + e], s);
    atomicAdd(&ws[slot + 64 + e], (float)cnt[e]);
  }
}

__global__ void finalize_kernel(const float* __restrict__ ws, float* __restrict__ out) {
  const int e = threadIdx.x;
  if (e < 64) {
    float imp = 0.f, cf = 0.f;
    #pragma unroll
    for (int s = 0; s < NSLOT; ++s) {
      imp += ws[s * 128 + e];
      cf  += ws[s * 128 + 64 + e];
    }
    out[OFF_IMP  + e] = imp * (1.0f / 32768.0f);
    out[OFF_LOAD + e] = cf  * (1.0f / 65536.0f);   // counts sum == B*S*K
  }
}

extern "C" void kernel_launch(void* const* d_in, const int* in_sizes, int n_in,
                              void* d_out, int out_size, void* d_ws, size_t ws_size,
                              hipStream_t stream) {
  (void)in_sizes; (void)n_in; (void)out_size; (void)ws_size;
  const float* x  = (const float*)d_in[0];   // [8,4096,1024]
  const float* Wg = (const float*)d_in[1];   // [4,1024]
  const float* We = (const float*)d_in[2];   // [64,1024]
  float* out = (float*)d_out;
  float* ws  = (float*)d_ws;                 // NSLOT x (64 importance + 64 counts)
  hipLaunchKernelGGL(prep_kernel, dim3(160), dim3(64), 0, stream, Wg, We, ws);
  hipLaunchKernelGGL(router_kernel, dim3(NBLOCKS), dim3(256), 0, stream, x, out, ws);
  hipLaunchKernelGGL(finalize_kernel, dim3(1), dim3(64), 0, stream, ws, out);
}